// Round 1
// baseline (86.414 us; speedup 1.0000x reference)
//
#include <hip/hip_runtime.h>
#include <math.h>

#define BB 4
#define SS 1024
#define XX 1024
#define CC 8
#define DD 2
#define WIDTH 16
#define DEPTH 4

#define NLUT 4096
#define RSCALE 16.0f          // grid spacing 1/16, domain [0, 256)
#define RSQRT_SCALE 4.0f      // sqrt(RSCALE): coords pre-scaled so fma gives r*RSCALE
#define GQ 8                  // queries per block

// tanh(v) = copysign(2/(1+exp(-2|v|)) - 1, v)
__device__ __forceinline__ float fast_tanh(float v) {
    float ax = __builtin_fabsf(v);
    float e  = __builtin_amdgcn_exp2f(ax * -2.885390081777927f); // exp(-2|v|)
    float t  = fmaf(2.0f, __builtin_amdgcn_rcpf(1.0f + e), -1.0f);
    return __builtin_copysignf(t, v);
}

// DPP move: cross-lane fetch on the VALU pipe (no LDS traffic).
// 0xB1 = quad_perm [1,0,3,2]  (xor 1)
// 0x4E = quad_perm [2,3,0,1]  (xor 2)
// 0x128 = row_ror:8           (xor 8 within 16-lane row)
template <int CTRL>
__device__ __forceinline__ float dpp_mov(float w) {
    return __int_as_float(
        __builtin_amdgcn_mov_dpp(__float_as_int(w), CTRL, 0xF, 0xF, true));
}

// ---- kernel 1: tabulate k = f(r); 64 blocks x 64 threads, one entry/thread ----
__global__ __launch_bounds__(64) void build_lut(
    const float* __restrict__ W_in, const float* __restrict__ b_in,
    const float* __restrict__ W_hid, const float* __restrict__ b_hid,
    const float* __restrict__ W_out, const float* __restrict__ b_out,
    float* __restrict__ lut)
{
    const int idx = blockIdx.x * 64 + threadIdx.x;   // 4096 total
    const float r = (float)idx * (1.0f / RSCALE);

    float h[WIDTH];
#pragma unroll
    for (int j = 0; j < WIDTH; ++j) h[j] = fmaf(r, W_in[j], b_in[j]);

#pragma unroll
    for (int l = 0; l < DEPTH; ++l) {
        const float* W  = W_hid + l * WIDTH * WIDTH;
        const float* bb = b_hid + l * WIDTH;
        float pre[WIDTH];
#pragma unroll
        for (int j = 0; j < WIDTH; ++j) pre[j] = bb[j];
#pragma unroll
        for (int i = 0; i < WIDTH; ++i) {
            const float hi = h[i];
#pragma unroll
            for (int j = 0; j < WIDTH; ++j)
                pre[j] = fmaf(hi, W[i * WIDTH + j], pre[j]);
        }
#pragma unroll
        for (int j = 0; j < WIDTH; ++j) h[j] += fast_tanh(pre[j]);
    }

    float k = b_out[0];
#pragma unroll
    for (int j = 0; j < WIDTH; ++j) k = fmaf(h[j], W_out[j], k);
    lut[idx] = k;
}

// ---- kernel 2: block = 8 query points; yu rows pinned in registers ----
__global__ __launch_bounds__(256) void ccl_main(
    const float* __restrict__ yu,     // (B,S,C+D)
    const float* __restrict__ x,      // (B,X,D)
    const float* __restrict__ lut_g,  // (NLUT) scalar LUT
    float* __restrict__ out)          // (B,X,C)
{
    __shared__ __align__(16) float2 lut2_s[NLUT];  // 32 KB: (f[i], f[i+1]-f[i])
    __shared__ float red[4 * 64];                  // 1 KB: [wave][lane]

    const int bx   = blockIdx.x;
    const int b    = bx / (XX / GQ);          // 512 blocks: 128 per batch
    const int xi0  = (bx % (XX / GQ)) * GQ;
    const int tid  = threadIdx.x;
    const int lane = tid & 63;
    const int wv   = tid >> 6;

    // stage LUT as (value, delta) pairs: 4 groups of 4 entries per thread
    {
        const float4* src = reinterpret_cast<const float4*>(lut_g);
        float4*       d4  = reinterpret_cast<float4*>(lut2_s);
#pragma unroll
        for (int i = 0; i < NLUT / 4 / 256; ++i) {
            const int g = tid + i * 256;              // float4 group 0..1023
            float4 v = src[g];
            float nxt = (g < NLUT / 4 - 1) ? lut_g[4 * g + 4] : v.w;
            d4[2 * g]     = make_float4(v.x, v.y - v.x, v.y, v.z - v.y);
            d4[2 * g + 1] = make_float4(v.z, v.w - v.z, v.w, nxt - v.w);
        }
    }

    // pin this thread's 4 s-points (y scaled by sqrt(RSCALE), u raw) in registers
    const float* yub = yu + (size_t)b * SS * (CC + DD);
    float2 yp[4];
    float  up[4][CC];
#pragma unroll
    for (int i = 0; i < 4; ++i) {
        const int s = tid + i * 256;
        const float2* row = reinterpret_cast<const float2*>(yub + (size_t)s * (CC + DD));
        float2 a0 = row[0], a1 = row[1], a2 = row[2], a3 = row[3];
        float2 yv = row[4];
        yp[i] = make_float2(yv.x * RSQRT_SCALE, yv.y * RSQRT_SCALE);
        up[i][0] = a0.x; up[i][1] = a0.y; up[i][2] = a1.x; up[i][3] = a1.y;
        up[i][4] = a2.x; up[i][5] = a2.y; up[i][6] = a3.x; up[i][7] = a3.y;
    }

    // query coords (block-uniform), pre-scaled
    float qx[GQ], qy[GQ];
    {
        const float* xp = x + ((size_t)b * XX + xi0) * DD;
#pragma unroll
        for (int q = 0; q < GQ; ++q) {
            qx[q] = xp[2 * q]     * RSQRT_SCALE;
            qy[q] = xp[2 * q + 1] * RSQRT_SCALE;
        }
    }

    __syncthreads();

    const bool b0 = (lane & 1)  != 0;
    const bool b1 = (lane & 2)  != 0;
    const bool b2 = (lane & 4)  != 0;
    const bool b3 = (lane & 8)  != 0;
    const bool b4 = (lane & 16) != 0;
    const bool b5 = (lane & 32) != 0;

    float vq[GQ];   // per-query: channel (lane&7) summed over this lane's 8-group

#pragma unroll
    for (int q = 0; q < GQ; ++q) {
        float acc[CC];
#pragma unroll
        for (int c = 0; c < CC; ++c) acc[c] = 0.0f;

#pragma unroll
        for (int i = 0; i < 4; ++i) {
            const float d0 = qx[q] - yp[i].x;
            const float d1 = qy[q] - yp[i].y;
            const float rf = fmaf(d0, d0, d1 * d1);   // = r * RSCALE exactly

            int ix = (int)rf;
            ix = min(ix, NLUT - 2);
            const float w  = rf - (float)ix;
            const float2 fd = lut2_s[ix];             // one ds_read_b64
            const float k  = fmaf(w, fd.y, fd.x);

#pragma unroll
            for (int c = 0; c < CC; ++c) acc[c] = fmaf(k, up[i][c], acc[c]);
        }

        // channel butterfly: xor1/xor2 on VALU pipe (DPP), xor4 via shfl
        float m[4];
#pragma unroll
        for (int i = 0; i < 4; ++i) {            // xor 1: keep ch 2i+b0
            float u = b0 ? acc[2 * i + 1] : acc[2 * i];
            float w = b0 ? acc[2 * i]     : acc[2 * i + 1];
            m[i] = u + dpp_mov<0xB1>(w);
        }
        float n[2];
#pragma unroll
        for (int j = 0; j < 2; ++j) {            // xor 2: keep 4j+2b1+b0
            float u = b1 ? m[2 * j + 1] : m[2 * j];
            float w = b1 ? m[2 * j]     : m[2 * j + 1];
            n[j] = u + dpp_mov<0x4E>(w);
        }
        {                                        // xor 4: keep ch = lane&7
            float u = b2 ? n[1] : n[0];
            float w = b2 ? n[0] : n[1];
            vq[q] = u + __shfl_xor(w, 4, 64);
        }
    }

    // query butterfly: fold q-dimension while reducing remaining lane bits.
    // xor8 on VALU (row_ror:8), xor16/xor32 via shfl.
    float m2[4];
#pragma unroll
    for (int i = 0; i < 4; ++i) {                // keep q-bit0 = lane-bit3
        float u = b3 ? vq[2 * i + 1] : vq[2 * i];
        float w = b3 ? vq[2 * i]     : vq[2 * i + 1];
        m2[i] = u + dpp_mov<0x128>(w);
    }
    float n2[2];
#pragma unroll
    for (int j = 0; j < 2; ++j) {                // keep q-bit1 = lane-bit4
        float u = b4 ? m2[2 * j + 1] : m2[2 * j];
        float w = b4 ? m2[2 * j]     : m2[2 * j + 1];
        n2[j] = u + __shfl_xor(w, 16, 64);
    }
    float p2;
    {                                            // keep q-bit2 = lane-bit5
        float u = b5 ? n2[1] : n2[0];
        float w = b5 ? n2[0] : n2[1];
        p2 = u + __shfl_xor(w, 32, 64);
    }
    // lane L of each wave now holds full-wave sum for q=(L>>3)&7, c=L&7

    red[wv * 64 + lane] = p2;
    __syncthreads();
    if (tid < 64) {
        const int q = tid >> 3;
        const int c = tid & 7;
        const float v = red[tid] + red[64 + tid] + red[128 + tid] + red[192 + tid];
        out[((size_t)b * XX + xi0 + q) * CC + c] = v * (1.0f / SS);
    }
}

extern "C" void kernel_launch(void* const* d_in, const int* in_sizes, int n_in,
                              void* d_out, int out_size, void* d_ws, size_t ws_size,
                              hipStream_t stream) {
    const float* yu    = (const float*)d_in[0];
    const float* x     = (const float*)d_in[1];
    const float* W_in  = (const float*)d_in[2];
    const float* b_in  = (const float*)d_in[3];
    const float* W_hid = (const float*)d_in[4];
    const float* b_hid = (const float*)d_in[5];
    const float* W_out = (const float*)d_in[6];
    const float* b_out = (const float*)d_in[7];
    float* out = (float*)d_out;
    float* lut = (float*)d_ws;        // 16 KB of scratch

    build_lut<<<dim3(NLUT / 64), dim3(64), 0, stream>>>(
        W_in, b_in, W_hid, b_hid, W_out, b_out, lut);

    ccl_main<<<dim3(BB * XX / GQ), dim3(256), 0, stream>>>(yu, x, lut, out);
}